// Round 3
// baseline (2218.591 us; speedup 1.0000x reference)
//
#include <hip/hip_runtime.h>
#include <math.h>

typedef unsigned short u16;
typedef short s16x8 __attribute__((ext_vector_type(8)));
typedef float f32x4 __attribute__((ext_vector_type(4)));

#define BM 128
#define BN 128
#define BK 32

__device__ __forceinline__ u16 f2bf(float f) {
    union { float f; unsigned u; } v; v.f = f;
    unsigned u = v.u + 0x7FFFu + ((v.u >> 16) & 1u);
    return (u16)(u >> 16);
}
__device__ __forceinline__ float bf2f(u16 u) {
    union { unsigned u; float f; } v; v.u = ((unsigned)u) << 16; return v.f;
}

__device__ __forceinline__ void g2lds16(const void* g, void* l) {
    __builtin_amdgcn_global_load_lds(
        (const __attribute__((address_space(1))) void*)g,
        (__attribute__((address_space(3))) void*)l, 16, 0, 0);
}

enum { E_F32 = 0, E_BF16 = 1, E_QKV = 2, E_SMIX = 3, E_TBF = 4, E_Y = 5 };

// C[m,n] = sum_k A[m,k] * B[n,k]   (both operands K-contiguous, "NT")
template<int EPI>
__global__ __launch_bounds__(256) void gemm_nt(
    const u16* __restrict__ A, const u16* __restrict__ B,
    long sAz, long sBz, int lda, int ldb,
    int M, int Ncols, int K,
    float* __restrict__ outf, u16* __restrict__ outb,
    u16* __restrict__ outb2, u16* __restrict__ outb3,
    const float* __restrict__ aux1f, const u16* __restrict__ aux1b,
    const float* __restrict__ chainp,
    long sOz, int ldc, float scale, int zbase)
{
    __shared__ __align__(16) u16 As[BM * BK];
    __shared__ __align__(16) u16 Bs[BN * BK];

    const int z    = blockIdx.z;
    const u16* Ab  = A + (long)z * sAz;
    const u16* Bb  = B + (long)z * sBz;
    const int tid  = threadIdx.x;
    const int lane = tid & 63;
    const int wid  = tid >> 6;
    const int m0   = blockIdx.x * BM;
    const int n0   = blockIdx.y * BN;
    const int wr   = (wid >> 1) * 64;
    const int wc   = (wid & 1) * 64;

    f32x4 zero = {0.f, 0.f, 0.f, 0.f};
    f32x4 acc[4][4];
#pragma unroll
    for (int i = 0; i < 4; ++i)
#pragma unroll
        for (int j = 0; j < 4; ++j) acc[i][j] = zero;

    const int srow = tid >> 2;
    const int scol = (tid & 3) * 8;
    int bn0 = n0 + srow;      if (bn0 > Ncols - 1) bn0 = Ncols - 1;
    int bn1 = n0 + 64 + srow; if (bn1 > Ncols - 1) bn1 = Ncols - 1;
    const u16* gA0 = Ab + (long)(m0 + srow) * lda + scol;
    const u16* gA1 = Ab + (long)(m0 + 64 + srow) * lda + scol;
    const u16* gB0 = Bb + (long)bn0 * ldb + scol;
    const u16* gB1 = Bb + (long)bn1 * ldb + scol;

    const int kq = (lane >> 4) * 8;
    const int fr = lane & 15;

    for (int k0 = 0; k0 < K; k0 += BK) {
        g2lds16(gA0 + k0, As + tid * 8);
        g2lds16(gA1 + k0, As + 2048 + tid * 8);
        g2lds16(gB0 + k0, Bs + tid * 8);
        g2lds16(gB1 + k0, Bs + 2048 + tid * 8);
        __syncthreads();
        s16x8 af[4], bfr[4];
#pragma unroll
        for (int i = 0; i < 4; ++i)
            af[i] = *(const s16x8*)(const void*)(As + (wr + i * 16 + fr) * BK + kq);
#pragma unroll
        for (int j = 0; j < 4; ++j)
            bfr[j] = *(const s16x8*)(const void*)(Bs + (wc + j * 16 + fr) * BK + kq);
#pragma unroll
        for (int i = 0; i < 4; ++i)
#pragma unroll
            for (int j = 0; j < 4; ++j)
                acc[i][j] = __builtin_amdgcn_mfma_f32_16x16x32_bf16(af[i], bfr[j], acc[i][j], 0, 0, 0);
        __syncthreads();
    }

    const int rbase = (lane >> 4) * 4;
    const int cidx  = lane & 15;
    float wgate = 0.f;
    if (EPI == E_Y) wgate = 1.f / (1.f + __expf(-chainp[0]));

#pragma unroll
    for (int i = 0; i < 4; ++i) {
#pragma unroll
        for (int r = 0; r < 4; ++r) {
            const int gm = m0 + wr + i * 16 + rbase + r;
#pragma unroll
            for (int j = 0; j < 4; ++j) {
                const int gn = n0 + wc + j * 16 + cidx;
                const float v = acc[i][j][r];
                if (EPI == E_F32) {
                    if (gn < Ncols) outf[(long)z * sOz + (long)gm * ldc + gn] = v * scale;
                } else if (EPI == E_BF16) {
                    if (gn < Ncols) outb[(long)z * sOz + (long)gm * ldc + gn] = f2bf(v * scale);
                } else if (EPI == E_QKV) {
                    const int b_ = gm >> 11, ntok = gm & 2047;
                    const int which = gn >> 9, h = (gn & 511) >> 6, d = gn & 63;
                    const long bh = (long)(b_ * 8 + h);
                    const u16 bv = f2bf(which == 0 ? v * scale : v);  // fold 1/sqrt(dk) into Q
                    if (which == 0)       outb [(bh * 2048 + ntok) * 64 + d] = bv;
                    else if (which == 1)  outb2[(bh * 2048 + ntok) * 64 + d] = bv;
                    else                  outb3[(bh * 64 + d) * 2048 + ntok] = bv;
                } else if (EPI == E_SMIX) {
                    const long off = (long)z * sOz + (long)gm * ldc + gn;
                    const float pre = bf2f(aux1b[off]);
                    outb[off] = f2bf(pre + 0.5f * __logf(v + 1e-6f));
                } else if (EPI == E_TBF) {
                    if (gn < Ncols) outb[(long)z * sOz + (long)gn * ldc + gm] = f2bf(v);
                } else if (EPI == E_Y) {
                    if (gn < Ncols) {
                        const float yv = v + wgate * aux1f[(long)z * sOz + (long)gm * 64 + gn];
                        const int zg = zbase + z;
                        const int b_ = zg >> 3, h = zg & 7;
                        outb[((long)(b_ * 2048 + gm)) * 512 + h * 64 + gn] = f2bf(yv);
                    }
                }
            }
        }
    }
}

__global__ __launch_bounds__(256) void cvt_f32_bf16(const float* __restrict__ in,
                                                    u16* __restrict__ out, long n) {
    long i = (long)blockIdx.x * 256 + threadIdx.x;
    if (i < n) out[i] = f2bf(in[i]);
}

// in: [R][C] f32  ->  out: [C][R] bf16
__global__ __launch_bounds__(256) void cvt_transpose(const float* __restrict__ in,
                                                     u16* __restrict__ out, int R, int C) {
    long i = (long)blockIdx.x * 256 + threadIdx.x;
    if (i < (long)R * C) {
        int c = (int)(i / R), r = (int)(i % R);
        out[i] = f2bf(in[(long)r * C + c]);
    }
}

// per-z transpose of 2048x2048 bf16
__global__ __launch_bounds__(256) void trans2048(const u16* __restrict__ in,
                                                 u16* __restrict__ out) {
    __shared__ u16 tile[64][65];
    const long z = blockIdx.z;
    const u16* I = in + z * (long)2048 * 2048;
    u16* O       = out + z * (long)2048 * 2048;
    const int bx = blockIdx.x * 64, by = blockIdx.y * 64;
    const int t = threadIdx.x, c = t & 63, r4 = t >> 6;
#pragma unroll
    for (int s = 0; s < 16; ++s) {
        int r = s * 4 + r4;
        tile[r][c] = I[(long)(by + r) * 2048 + bx + c];
    }
    __syncthreads();
#pragma unroll
    for (int s = 0; s < 16; ++s) {
        int r = s * 4 + r4;
        O[(long)(bx + r) * 2048 + by + c] = tile[c][r];
    }
}

// One block per row (2048 bf16). MODE 0: A = softmax(S).
// MODE 1: A = softmax(S);  PreOut = 0.5*Spre + 0.75*S + 0.5*logaddexp(Spre,S)
//         (PreOut may alias Spre: per-thread in-place).
template<int MODE>
__global__ __launch_bounds__(256) void row_softmax_bf(
    const u16* __restrict__ S, const u16* __restrict__ Spre,
    u16* __restrict__ A, u16* __restrict__ PreOut)
{
    const long row = blockIdx.x;
    const u16* p = S + row * 2048;
    const int t = threadIdx.x;
    s16x8 xv = *(const s16x8*)(const void*)(p + t * 8);
    float x[8];
#pragma unroll
    for (int e = 0; e < 8; ++e) x[e] = bf2f((u16)xv[e]);
    float m = x[0];
#pragma unroll
    for (int e = 1; e < 8; ++e) m = fmaxf(m, x[e]);
#pragma unroll
    for (int off = 32; off >= 1; off >>= 1) m = fmaxf(m, __shfl_xor(m, off));
    __shared__ float red[8];
    if ((t & 63) == 0) red[t >> 6] = m;
    __syncthreads();
    m = fmaxf(fmaxf(red[0], red[1]), fmaxf(red[2], red[3]));
    float s = 0.f, ee[8];
#pragma unroll
    for (int e = 0; e < 8; ++e) { ee[e] = __expf(x[e] - m); s += ee[e]; }
#pragma unroll
    for (int off = 32; off >= 1; off >>= 1) s += __shfl_xor(s, off);
    if ((t & 63) == 0) red[4 + (t >> 6)] = s;
    __syncthreads();
    s = red[4] + red[5] + red[6] + red[7];
    const float inv = 1.f / s;
    s16x8 o;
#pragma unroll
    for (int e = 0; e < 8; ++e) o[e] = (short)f2bf(ee[e] * inv);
    *(s16x8*)(void*)(A + row * 2048 + t * 8) = o;

    if (MODE == 1) {
        s16x8 pv = *(const s16x8*)(const void*)(Spre + row * 2048 + t * 8);
        s16x8 po;
#pragma unroll
        for (int e = 0; e < 8; ++e) {
            const float s1 = bf2f((u16)pv[e]);
            const float s2 = x[e];
            const float mx = fmaxf(s1, s2);
            const float lae = mx + log1pf(__expf(-fabsf(s1 - s2)));
            po[e] = (short)f2bf(0.5f * s1 + 0.75f * s2 + 0.5f * lae);
        }
        *(s16x8*)(void*)(PreOut + row * 2048 + t * 8) = po;
    }
}

extern "C" void kernel_launch(void* const* d_in, const int* in_sizes, int n_in,
                              void* d_out, int out_size, void* d_ws, size_t ws_size,
                              hipStream_t stream) {
    const float* x  = (const float*)d_in[0];
    const float* W1 = (const float*)d_in[1];
    const float* W2 = (const float*)d_in[2];
    const float* Wp = (const float*)d_in[3];
    const float* ch = (const float*)d_in[4];

    const int Bq = 2, N = 2048, D = 512, dk = 64, Z = 16;
    const long NN = (long)N * N;
    const long ND = (long)N * dk;
    (void)in_sizes; (void)n_in; (void)out_size;

    size_t ws_avail = ws_size ? ws_size : (size_t)-1;  // defensive: 0 => assume ample

    char* w = (char*)d_ws;
    size_t off = 0;
    auto alc = [&](size_t bytes) -> void* {
        void* p = w + off;
        off += (bytes + 255) & ~(size_t)255;
        return p;
    };

    // ---- persistent (~36 MiB) ----
    u16* xb   = (u16*)alc((long)Bq * N * D * 2);
    u16* W1t  = (u16*)alc((long)3 * D * D * 2);
    u16* W2t  = (u16*)alc((long)3 * D * D * 2);
    u16* Wpt  = (u16*)alc((long)D * D * 2);
    u16* Q1   = (u16*)alc(Z * ND * 2);
    u16* K1   = (u16*)alc(Z * ND * 2);
    u16* V1t  = (u16*)alc(Z * ND * 2);
    u16* Q2   = (u16*)alc(Z * ND * 2);
    u16* K2   = (u16*)alc(Z * ND * 2);
    u16* V2t  = (u16*)alc(Z * ND * 2);
    u16* y    = (u16*)alc((long)Bq * N * D * 2);
    const size_t persist = off;

    // ---- per-z-group buffers: pick largest G in {16,8,4,2,1} that fits ----
    const size_t perz = 5 * (size_t)(NN * 2) + 2 * (size_t)(ND * 2) + (size_t)(ND * 4) + 4096;
    int G = 16;
    while (G > 1 && persist + (size_t)G * perz + 65536 > ws_avail) G >>= 1;

    u16*  S1b = (u16*)alc((size_t)G * NN * 2);   // S1 -> Pre -> Smix
    u16*  S2b = (u16*)alc((size_t)G * NN * 2);   // S2 -> (free) -> A2t
    u16*  A1  = (u16*)alc((size_t)G * NN * 2);
    u16*  A2  = (u16*)alc((size_t)G * NN * 2);
    u16*  C1  = (u16*)alc((size_t)G * NN * 2);   // chain product -> final A
    u16*  t1t = (u16*)alc((size_t)G * ND * 2);
    u16*  t2t = (u16*)alc((size_t)G * ND * 2);
    float* yc = (float*)alc((size_t)G * ND * 4);
    u16*  A2t = S2b;

    const dim3 blk(256);
    const float iscale = 0.125f;  // 1/sqrt(64)

    cvt_f32_bf16<<<(unsigned)(((long)Bq * N * D + 255) / 256), blk, 0, stream>>>(x, xb, (long)Bq * N * D);
    cvt_transpose<<<(3 * D * D + 255) / 256, blk, 0, stream>>>(W1, W1t, D, 3 * D);
    cvt_transpose<<<(3 * D * D + 255) / 256, blk, 0, stream>>>(W2, W2t, D, 3 * D);
    cvt_transpose<<<(D * D + 255) / 256, blk, 0, stream>>>(Wp, Wpt, D, D);

    gemm_nt<E_QKV><<<dim3(32, 12, 1), blk, 0, stream>>>(
        xb, W1t, 0L, 0L, D, D, Bq * N, 3 * D, D,
        nullptr, Q1, K1, V1t, nullptr, nullptr, nullptr, 0L, 0, iscale, 0);
    gemm_nt<E_QKV><<<dim3(32, 12, 1), blk, 0, stream>>>(
        xb, W2t, 0L, 0L, D, D, Bq * N, 3 * D, D,
        nullptr, Q2, K2, V2t, nullptr, nullptr, nullptr, 0L, 0, iscale, 0);

    for (int zb = 0; zb < Z; zb += G) {
        const u16* Q1z = Q1 + (long)zb * ND;
        const u16* K1z = K1 + (long)zb * ND;
        const u16* V1z = V1t + (long)zb * ND;
        const u16* Q2z = Q2 + (long)zb * ND;
        const u16* K2z = K2 + (long)zb * ND;
        const u16* V2z = V2t + (long)zb * ND;

        // S1 = Q1 K1^T (scale folded into Q), bf16
        gemm_nt<E_BF16><<<dim3(16, 16, G), blk, 0, stream>>>(
            Q1z, K1z, ND, ND, dk, dk, N, N, dk,
            nullptr, S1b, nullptr, nullptr, nullptr, nullptr, nullptr, NN, N, 1.f, 0);
        gemm_nt<E_BF16><<<dim3(16, 16, G), blk, 0, stream>>>(
            Q2z, K2z, ND, ND, dk, dk, N, N, dk,
            nullptr, S2b, nullptr, nullptr, nullptr, nullptr, nullptr, NN, N, 1.f, 0);

        // A1 = softmax(S1); then A2 = softmax(S2) and Pre -> overwrite S1b
        row_softmax_bf<0><<<G * N, blk, 0, stream>>>(S1b, nullptr, A1, nullptr);
        row_softmax_bf<1><<<G * N, blk, 0, stream>>>(S2b, S1b, A2, S1b);

        // A2t (into S2b region, free now)
        trans2048<<<dim3(32, 32, G), blk, 0, stream>>>(A2, A2t);

        // C1 = A1 @ A2
        gemm_nt<E_BF16><<<dim3(16, 16, G), blk, 0, stream>>>(
            A1, A2t, NN, NN, N, N, N, N, N,
            nullptr, C1, nullptr, nullptr, nullptr, nullptr, nullptr, NN, N, 1.f, 0);
        // C2 = C1 @ A2; Smix = Pre + 0.5*log(C2+eps) -> overwrite S1b
        gemm_nt<E_SMIX><<<dim3(16, 16, G), blk, 0, stream>>>(
            C1, A2t, NN, NN, N, N, N, N, N,
            nullptr, S1b, nullptr, nullptr, nullptr, S1b, nullptr, NN, N, 1.f, 0);
        // A = softmax(Smix) -> reuse C1 region
        row_softmax_bf<0><<<G * N, blk, 0, stream>>>(S1b, nullptr, C1, nullptr);

        // transport chain: t1t = (A2 @ v2)^T, t2t = (A2 @ t1)^T   [dk][N] layouts
        gemm_nt<E_TBF><<<dim3(16, 1, G), blk, 0, stream>>>(
            A2, V2z, NN, ND, N, N, N, dk, N,
            nullptr, t1t, nullptr, nullptr, nullptr, nullptr, nullptr, ND, N, 1.f, 0);
        gemm_nt<E_TBF><<<dim3(16, 1, G), blk, 0, stream>>>(
            A2, t1t, NN, ND, N, N, N, dk, N,
            nullptr, t2t, nullptr, nullptr, nullptr, nullptr, nullptr, ND, N, 1.f, 0);
        // yc = A1 @ t2
        gemm_nt<E_F32><<<dim3(16, 1, G), blk, 0, stream>>>(
            A1, t2t, NN, ND, N, N, N, dk, N,
            yc, nullptr, nullptr, nullptr, nullptr, nullptr, nullptr, ND, dk, 1.f, 0);
        // y = A @ v1 + sigmoid(chain)*yc  -> bf16 [B,N,D]
        gemm_nt<E_Y><<<dim3(16, 1, G), blk, 0, stream>>>(
            C1, V1z, NN, ND, N, N, N, dk, N,
            nullptr, y, nullptr, nullptr, yc, nullptr, ch, ND, dk, 1.f, zb);
    }

    // out = y @ Wproj   (f32)
    gemm_nt<E_F32><<<dim3(32, 4, 1), blk, 0, stream>>>(
        y, Wpt, 0L, 0L, D, D, Bq * N, D, D,
        (float*)d_out, nullptr, nullptr, nullptr, nullptr, nullptr, nullptr, 0L, D, 1.f, 0);
}

// Round 4
// 1760.957 us; speedup vs baseline: 1.2599x; 1.2599x over previous
//
#include <hip/hip_runtime.h>
#include <math.h>

typedef unsigned short u16;
typedef short s16x8 __attribute__((ext_vector_type(8)));
typedef float f32x4 __attribute__((ext_vector_type(4)));

#define BM 128
#define BN 128
#define BK 32

__device__ __forceinline__ u16 f2bf(float f) {
    union { float f; unsigned u; } v; v.f = f;
    unsigned u = v.u + 0x7FFFu + ((v.u >> 16) & 1u);
    return (u16)(u >> 16);
}
__device__ __forceinline__ float bf2f(u16 u) {
    union { unsigned u; float f; } v; v.u = ((unsigned)u) << 16; return v.f;
}

__device__ __forceinline__ void g2lds16(const void* g, void* l) {
    __builtin_amdgcn_global_load_lds(
        (const __attribute__((address_space(1))) void*)g,
        (__attribute__((address_space(3))) void*)l, 16, 0, 0);
}

enum { E_F32 = 0, E_BF16 = 1, E_QKV = 2, E_SMIX = 3, E_Y = 5 };

// C[m,n] = sum_k A[m,k] * B[n,k]   (both operands K-contiguous, "NT")
// 2-phase double-buffered: STAGE(t+1) issued before compute(t); one barrier/K-step.
template<int EPI>
__global__ __launch_bounds__(256) void gemm_nt(
    const u16* __restrict__ A, const u16* __restrict__ B,
    long sAz, long sBz, int lda, int ldb,
    int M, int Ncols, int K,
    float* __restrict__ outf, u16* __restrict__ outb,
    u16* __restrict__ outb2, u16* __restrict__ outb3,
    const float* __restrict__ aux1f, const u16* __restrict__ aux1b,
    const float* __restrict__ chainp,
    long sOz, int ldc, float scale, int zbase)
{
    __shared__ __align__(16) u16 As[2][BM * BK];
    __shared__ __align__(16) u16 Bs[2][BN * BK];

    const int z    = blockIdx.z;
    const u16* Ab  = A + (long)z * sAz;
    const u16* Bb  = B + (long)z * sBz;
    const int tid  = threadIdx.x;
    const int lane = tid & 63;
    const int wid  = tid >> 6;
    const int m0   = blockIdx.x * BM;
    const int n0   = blockIdx.y * BN;
    const int wr   = (wid >> 1) * 64;
    const int wc   = (wid & 1) * 64;

    f32x4 zero = {0.f, 0.f, 0.f, 0.f};
    f32x4 acc[4][4];
#pragma unroll
    for (int i = 0; i < 4; ++i)
#pragma unroll
        for (int j = 0; j < 4; ++j) acc[i][j] = zero;

    const int srow = tid >> 2;
    const int scol = (tid & 3) * 8;
    int bn0 = n0 + srow;      if (bn0 > Ncols - 1) bn0 = Ncols - 1;
    int bn1 = n0 + 64 + srow; if (bn1 > Ncols - 1) bn1 = Ncols - 1;
    const u16* gA0 = Ab + (long)(m0 + srow) * lda + scol;
    const u16* gA1 = Ab + (long)(m0 + 64 + srow) * lda + scol;
    const u16* gB0 = Bb + (long)bn0 * ldb + scol;
    const u16* gB1 = Bb + (long)bn1 * ldb + scol;

    const int kq = (lane >> 4) * 8;
    const int fr = lane & 15;

#define STAGE(buf, kk)                                  \
    do {                                                \
        g2lds16(gA0 + (kk), &As[buf][tid * 8]);         \
        g2lds16(gA1 + (kk), &As[buf][2048 + tid * 8]);  \
        g2lds16(gB0 + (kk), &Bs[buf][tid * 8]);         \
        g2lds16(gB1 + (kk), &Bs[buf][2048 + tid * 8]);  \
    } while (0)

    STAGE(0, 0);
    __syncthreads();  // compiler drains vmcnt(0) before s_barrier
    int cur = 0;
    for (int k0 = 0; k0 < K; k0 += BK) {
        if (k0 + BK < K) STAGE(cur ^ 1, k0 + BK);  // prefetch overlaps compute
        s16x8 af[4], bfr[4];
#pragma unroll
        for (int i = 0; i < 4; ++i)
            af[i] = *(const s16x8*)(const void*)(&As[cur][(wr + i * 16 + fr) * BK + kq]);
#pragma unroll
        for (int j = 0; j < 4; ++j)
            bfr[j] = *(const s16x8*)(const void*)(&Bs[cur][(wc + j * 16 + fr) * BK + kq]);
#pragma unroll
        for (int i = 0; i < 4; ++i)
#pragma unroll
            for (int j = 0; j < 4; ++j)
                acc[i][j] = __builtin_amdgcn_mfma_f32_16x16x32_bf16(af[i], bfr[j], acc[i][j], 0, 0, 0);
        __syncthreads();  // drains prefetch vmcnt + protects LDS reads
        cur ^= 1;
    }
#undef STAGE

    const int rbase = (lane >> 4) * 4;
    const int cidx  = lane & 15;
    float wgate = 0.f;
    if (EPI == E_Y) wgate = 1.f / (1.f + __expf(-chainp[0]));

#pragma unroll
    for (int i = 0; i < 4; ++i) {
#pragma unroll
        for (int r = 0; r < 4; ++r) {
            const int gm = m0 + wr + i * 16 + rbase + r;
#pragma unroll
            for (int j = 0; j < 4; ++j) {
                const int gn = n0 + wc + j * 16 + cidx;
                const float v = acc[i][j][r];
                if (EPI == E_F32) {
                    if (gn < Ncols) outf[(long)z * sOz + (long)gm * ldc + gn] = v * scale;
                } else if (EPI == E_BF16) {
                    if (gn < Ncols) outb[(long)z * sOz + (long)gm * ldc + gn] = f2bf(v * scale);
                } else if (EPI == E_QKV) {
                    const int b_ = gm >> 11, ntok = gm & 2047;
                    const int which = gn >> 9, h = (gn & 511) >> 6, d = gn & 63;
                    const long bh = (long)(b_ * 8 + h);
                    const u16 bv = f2bf(which == 0 ? v * scale : v);  // fold 1/sqrt(dk) into Q
                    if (which == 0)       outb [(bh * 2048 + ntok) * 64 + d] = bv;
                    else if (which == 1)  outb2[(bh * 2048 + ntok) * 64 + d] = bv;
                    else                  outb3[(bh * 64 + d) * 2048 + ntok] = bv;
                } else if (EPI == E_SMIX) {
                    const long off = (long)z * sOz + (long)gm * ldc + gn;
                    const float pre = bf2f(aux1b[off]);
                    outb[off]  = f2bf(pre + 0.5f * __logf(v + 1e-6f));  // Smix
                    outb2[off] = f2bf(v);                               // C2 (for y_chain = C2 @ v2)
                } else if (EPI == E_Y) {
                    if (gn < Ncols) {
                        const float yv = v + wgate * aux1f[(long)z * sOz + (long)gm * 64 + gn];
                        const int zg = zbase + z;
                        const int b_ = zg >> 3, h = zg & 7;
                        outb[((long)(b_ * 2048 + gm)) * 512 + h * 64 + gn] = f2bf(yv);
                    }
                }
            }
        }
    }
}

__global__ __launch_bounds__(256) void cvt_f32_bf16(const float* __restrict__ in,
                                                    u16* __restrict__ out, long n) {
    long i = (long)blockIdx.x * 256 + threadIdx.x;
    if (i < n) out[i] = f2bf(in[i]);
}

// in: [R][C] f32  ->  out: [C][R] bf16
__global__ __launch_bounds__(256) void cvt_transpose(const float* __restrict__ in,
                                                     u16* __restrict__ out, int R, int C) {
    long i = (long)blockIdx.x * 256 + threadIdx.x;
    if (i < (long)R * C) {
        int c = (int)(i / R), r = (int)(i % R);
        out[i] = f2bf(in[(long)r * C + c]);
    }
}

// per-z transpose of 2048x2048 bf16
__global__ __launch_bounds__(256) void trans2048(const u16* __restrict__ in,
                                                 u16* __restrict__ out) {
    __shared__ u16 tile[64][65];
    const long z = blockIdx.z;
    const u16* I = in + z * (long)2048 * 2048;
    u16* O       = out + z * (long)2048 * 2048;
    const int bx = blockIdx.x * 64, by = blockIdx.y * 64;
    const int t = threadIdx.x, c = t & 63, r4 = t >> 6;
#pragma unroll
    for (int s = 0; s < 16; ++s) {
        int r = s * 4 + r4;
        tile[r][c] = I[(long)(by + r) * 2048 + bx + c];
    }
    __syncthreads();
#pragma unroll
    for (int s = 0; s < 16; ++s) {
        int r = s * 4 + r4;
        O[(long)(bx + r) * 2048 + by + c] = tile[c][r];
    }
}

// One block per row (2048 bf16). MODE 0: A = softmax(S).
// MODE 1: A = softmax(S);  PreOut = 0.5*Spre + 0.75*S + 0.5*logaddexp(Spre,S)
//         (PreOut may alias Spre: per-thread in-place).
template<int MODE>
__global__ __launch_bounds__(256) void row_softmax_bf(
    const u16* __restrict__ S, const u16* __restrict__ Spre,
    u16* __restrict__ A, u16* __restrict__ PreOut)
{
    const long row = blockIdx.x;
    const u16* p = S + row * 2048;
    const int t = threadIdx.x;
    s16x8 xv = *(const s16x8*)(const void*)(p + t * 8);
    float x[8];
#pragma unroll
    for (int e = 0; e < 8; ++e) x[e] = bf2f((u16)xv[e]);
    float m = x[0];
#pragma unroll
    for (int e = 1; e < 8; ++e) m = fmaxf(m, x[e]);
#pragma unroll
    for (int off = 32; off >= 1; off >>= 1) m = fmaxf(m, __shfl_xor(m, off));
    __shared__ float red[8];
    if ((t & 63) == 0) red[t >> 6] = m;
    __syncthreads();
    m = fmaxf(fmaxf(red[0], red[1]), fmaxf(red[2], red[3]));
    float s = 0.f, ee[8];
#pragma unroll
    for (int e = 0; e < 8; ++e) { ee[e] = __expf(x[e] - m); s += ee[e]; }
#pragma unroll
    for (int off = 32; off >= 1; off >>= 1) s += __shfl_xor(s, off);
    if ((t & 63) == 0) red[4 + (t >> 6)] = s;
    __syncthreads();
    s = red[4] + red[5] + red[6] + red[7];
    const float inv = 1.f / s;
    s16x8 o;
#pragma unroll
    for (int e = 0; e < 8; ++e) o[e] = (short)f2bf(ee[e] * inv);
    *(s16x8*)(void*)(A + row * 2048 + t * 8) = o;

    if (MODE == 1) {
        s16x8 pv = *(const s16x8*)(const void*)(Spre + row * 2048 + t * 8);
        s16x8 po;
#pragma unroll
        for (int e = 0; e < 8; ++e) {
            const float s1 = bf2f((u16)pv[e]);
            const float s2 = x[e];
            const float mx = fmaxf(s1, s2);
            const float lae = mx + log1pf(__expf(-fabsf(s1 - s2)));
            po[e] = (short)f2bf(0.5f * s1 + 0.75f * s2 + 0.5f * lae);
        }
        *(s16x8*)(void*)(PreOut + row * 2048 + t * 8) = po;
    }
}

extern "C" void kernel_launch(void* const* d_in, const int* in_sizes, int n_in,
                              void* d_out, int out_size, void* d_ws, size_t ws_size,
                              hipStream_t stream) {
    const float* x  = (const float*)d_in[0];
    const float* W1 = (const float*)d_in[1];
    const float* W2 = (const float*)d_in[2];
    const float* Wp = (const float*)d_in[3];
    const float* ch = (const float*)d_in[4];

    const int Bq = 2, N = 2048, D = 512, dk = 64, Z = 16;
    const long NN = (long)N * N;
    const long ND = (long)N * dk;
    (void)in_sizes; (void)n_in; (void)out_size;

    size_t ws_avail = ws_size ? ws_size : (size_t)-1;  // defensive: 0 => assume ample

    char* w = (char*)d_ws;
    size_t off = 0;
    auto alc = [&](size_t bytes) -> void* {
        void* p = w + off;
        off += (bytes + 255) & ~(size_t)255;
        return p;
    };

    // ---- persistent (~36 MiB) ----
    u16* xb   = (u16*)alc((long)Bq * N * D * 2);
    u16* W1t  = (u16*)alc((long)3 * D * D * 2);
    u16* W2t  = (u16*)alc((long)3 * D * D * 2);
    u16* Wpt  = (u16*)alc((long)D * D * 2);
    u16* Q1   = (u16*)alc(Z * ND * 2);
    u16* K1   = (u16*)alc(Z * ND * 2);
    u16* V1t  = (u16*)alc(Z * ND * 2);
    u16* Q2   = (u16*)alc(Z * ND * 2);
    u16* K2   = (u16*)alc(Z * ND * 2);
    u16* V2t  = (u16*)alc(Z * ND * 2);
    u16* y    = (u16*)alc((long)Bq * N * D * 2);
    const size_t persist = off;

    // ---- per-z-group: 4 NxN bf16 buffers + yc; largest G in {16,8,4,2,1} that fits ----
    const size_t perz = 4 * (size_t)(NN * 2) + (size_t)(ND * 4) + 4096;
    int G = 16;
    while (G > 1 && persist + (size_t)G * perz + 65536 > ws_avail) G >>= 1;

    u16*  S1b = (u16*)alc((size_t)G * NN * 2);   // S1 -> Pre -> Smix
    u16*  S2b = (u16*)alc((size_t)G * NN * 2);   // S2 -> A2t
    u16*  A1b = (u16*)alc((size_t)G * NN * 2);   // A1 -> C2
    u16*  C1b = (u16*)alc((size_t)G * NN * 2);   // A2 -> C1 -> final A
    float* yc = (float*)alc((size_t)G * ND * 4);

    const dim3 blk(256);
    const float iscale = 0.125f;  // 1/sqrt(64)

    cvt_f32_bf16<<<(unsigned)(((long)Bq * N * D + 255) / 256), blk, 0, stream>>>(x, xb, (long)Bq * N * D);
    cvt_transpose<<<(3 * D * D + 255) / 256, blk, 0, stream>>>(W1, W1t, D, 3 * D);
    cvt_transpose<<<(3 * D * D + 255) / 256, blk, 0, stream>>>(W2, W2t, D, 3 * D);
    cvt_transpose<<<(D * D + 255) / 256, blk, 0, stream>>>(Wp, Wpt, D, D);

    gemm_nt<E_QKV><<<dim3(32, 12, 1), blk, 0, stream>>>(
        xb, W1t, 0L, 0L, D, D, Bq * N, 3 * D, D,
        nullptr, Q1, K1, V1t, nullptr, nullptr, nullptr, 0L, 0, iscale, 0);
    gemm_nt<E_QKV><<<dim3(32, 12, 1), blk, 0, stream>>>(
        xb, W2t, 0L, 0L, D, D, Bq * N, 3 * D, D,
        nullptr, Q2, K2, V2t, nullptr, nullptr, nullptr, 0L, 0, iscale, 0);

    for (int zb = 0; zb < Z; zb += G) {
        const u16* Q1z = Q1 + (long)zb * ND;
        const u16* K1z = K1 + (long)zb * ND;
        const u16* V1z = V1t + (long)zb * ND;
        const u16* Q2z = Q2 + (long)zb * ND;
        const u16* K2z = K2 + (long)zb * ND;
        const u16* V2z = V2t + (long)zb * ND;

        // S1 = Q1 K1^T (scale folded into Q) -> S1b ; S2 -> S2b  (bf16)
        gemm_nt<E_BF16><<<dim3(16, 16, G), blk, 0, stream>>>(
            Q1z, K1z, ND, ND, dk, dk, N, N, dk,
            nullptr, S1b, nullptr, nullptr, nullptr, nullptr, nullptr, NN, N, 1.f, 0);
        gemm_nt<E_BF16><<<dim3(16, 16, G), blk, 0, stream>>>(
            Q2z, K2z, ND, ND, dk, dk, N, N, dk,
            nullptr, S2b, nullptr, nullptr, nullptr, nullptr, nullptr, NN, N, 1.f, 0);

        // A1 = softmax(S1) -> A1b ; A2 = softmax(S2) -> C1b, Pre -> S1b (in-place)
        row_softmax_bf<0><<<G * N, blk, 0, stream>>>(S1b, nullptr, A1b, nullptr);
        row_softmax_bf<1><<<G * N, blk, 0, stream>>>(S2b, S1b, C1b, S1b);

        // A2t: C1b(A2) -> S2b
        trans2048<<<dim3(32, 32, G), blk, 0, stream>>>(C1b, S2b);

        // C1 = A1 @ A2  -> C1b (A2 copy dead after transpose)
        gemm_nt<E_BF16><<<dim3(16, 16, G), blk, 0, stream>>>(
            A1b, S2b, NN, NN, N, N, N, N, N,
            nullptr, C1b, nullptr, nullptr, nullptr, nullptr, nullptr, NN, N, 1.f, 0);
        // C2 = C1 @ A2 ; Smix = Pre + 0.5*log(C2+eps) -> S1b ; C2 bf16 -> A1b
        gemm_nt<E_SMIX><<<dim3(16, 16, G), blk, 0, stream>>>(
            C1b, S2b, NN, NN, N, N, N, N, N,
            nullptr, S1b, A1b, nullptr, nullptr, S1b, nullptr, NN, N, 1.f, 0);
        // A = softmax(Smix) -> C1b
        row_softmax_bf<0><<<G * N, blk, 0, stream>>>(S1b, nullptr, C1b, nullptr);

        // y_chain = C2 @ v2  (f32 [z][N][64])
        gemm_nt<E_F32><<<dim3(16, 1, G), blk, 0, stream>>>(
            A1b, V2z, NN, ND, N, N, N, dk, N,
            yc, nullptr, nullptr, nullptr, nullptr, nullptr, nullptr, ND, dk, 1.f, 0);
        // y = A @ v1 + sigmoid(chain)*y_chain  -> bf16 [B,N,D]
        gemm_nt<E_Y><<<dim3(16, 1, G), blk, 0, stream>>>(
            C1b, V1z, NN, ND, N, N, N, dk, N,
            nullptr, y, nullptr, nullptr, yc, nullptr, ch, ND, dk, 1.f, zb);
    }

    // out = y @ Wproj   (f32)
    gemm_nt<E_F32><<<dim3(32, 4, 1), blk, 0, stream>>>(
        y, Wpt, 0L, 0L, D, D, Bq * N, D, D,
        (float*)d_out, nullptr, nullptr, nullptr, nullptr, nullptr, nullptr, 0L, D, 1.f, 0);
}

// Round 5
// 1473.450 us; speedup vs baseline: 1.5057x; 1.1951x over previous
//
#include <hip/hip_runtime.h>
#include <math.h>

typedef unsigned short u16;
typedef short s16x8 __attribute__((ext_vector_type(8)));
typedef float f32x4 __attribute__((ext_vector_type(4)));

#define BM 128
#define BN 128
#define BK 32

__device__ __forceinline__ u16 f2bf(float f) {
    union { float f; unsigned u; } v; v.f = f;
    unsigned u = v.u + 0x7FFFu + ((v.u >> 16) & 1u);
    return (u16)(u >> 16);
}
__device__ __forceinline__ float bf2f(u16 u) {
    union { unsigned u; float f; } v; v.u = ((unsigned)u) << 16; return v.f;
}

__device__ __forceinline__ void g2lds16(const void* g, void* l) {
    __builtin_amdgcn_global_load_lds(
        (const __attribute__((address_space(1))) void*)g,
        (__attribute__((address_space(3))) void*)l, 16, 0, 0);
}

enum { E_F32 = 0, E_BF16 = 1, E_QKV = 2, E_SMIX = 3, E_Y = 5 };

// ============================================================================
// 256x256-tile, BK=64, 8-wave counted-vmcnt pipelined GEMM (chain GEMMs).
// C[m,n] = sum_k A[m,k]*B[n,k], M=N=2048 exact multiples of 256, K mult of 64.
// Schedule per K-tile T: STAGE(T+1) -> vmcnt(8) (T's loads done, T+1 in
// flight ACROSS the barrier) -> s_barrier -> 64 MFMA -> s_barrier.
// LDS reads use XOR swizzle byte^=(row&7)<<4; global_load_lds dest stays
// linear, source pre-swizzled with the same involution (rule #21).
// ============================================================================
template<int EPI>
__global__ __launch_bounds__(512) void gemm256_nt(
    const u16* __restrict__ A, const u16* __restrict__ B,
    long sAz, long sBz, int lda, int ldb, int K,
    u16* __restrict__ outb, u16* __restrict__ outb2,
    const u16* __restrict__ aux1b, long sOz, int ldc)
{
    __shared__ __align__(16) u16 As[2][2][8192];  // [dbuf][half][128 rows x 64 k]
    __shared__ __align__(16) u16 Bs[2][2][8192];

    const int z   = blockIdx.z;
    const u16* Ab = A + (long)z * sAz;
    const u16* Bb = B + (long)z * sBz;
    const int t    = threadIdx.x;
    const int lane = t & 63;
    const int wid  = t >> 6;
    const int wm   = wid >> 2;       // 0..1
    const int wn   = wid & 3;        // 0..3
    const int fr   = lane & 15;
    const int g4   = lane >> 4;
    const int m0   = blockIdx.x * 256;
    const int n0   = blockIdx.y * 256;

    // ---- staging addresses (linear LDS dest, inverse-swizzled global src) ----
    const int r0 = t >> 3;                         // 0..63 row within 64-row slab
    const int xc = ((t & 7) ^ (r0 & 7)) * 8;       // swizzled source column (elems)
    const u16* pA0 = Ab + (long)(m0 + r0) * lda + xc;
    const u16* pA1 = Ab + (long)(m0 + 64 + r0) * lda + xc;
    const u16* pA2 = Ab + (long)(m0 + 128 + r0) * lda + xc;
    const u16* pA3 = Ab + (long)(m0 + 192 + r0) * lda + xc;
    const u16* pB0 = Bb + (long)(n0 + r0) * ldb + xc;
    const u16* pB1 = Bb + (long)(n0 + 64 + r0) * ldb + xc;
    const u16* pB2 = Bb + (long)(n0 + 128 + r0) * ldb + xc;
    const u16* pB3 = Bb + (long)(n0 + 192 + r0) * ldb + xc;
    const int d0 = t * 8;          // elements; l=0 slab
    const int d1 = t * 8 + 4096;   // l=1 slab

#define STAGE256(d, kk)                        \
    do {                                       \
        g2lds16(pA0 + (kk), &As[d][0][d0]);    \
        g2lds16(pA1 + (kk), &As[d][0][d1]);    \
        g2lds16(pA2 + (kk), &As[d][1][d0]);    \
        g2lds16(pA3 + (kk), &As[d][1][d1]);    \
        g2lds16(pB0 + (kk), &Bs[d][0][d0]);    \
        g2lds16(pB1 + (kk), &Bs[d][0][d1]);    \
        g2lds16(pB2 + (kk), &Bs[d][1][d0]);    \
        g2lds16(pB3 + (kk), &Bs[d][1][d1]);    \
    } while (0)

    // ---- swizzled ds_read base offsets (elements) ----
    const int swz  = fr & 7;
    const int rbS0 = fr * 64 + ((g4 ^ swz) * 8);        // k-step s=0
    const int rbS1 = fr * 64 + (((4 + g4) ^ swz) * 8);  // k-step s=1

    f32x4 acc[8][4];
#pragma unroll
    for (int i = 0; i < 8; ++i)
#pragma unroll
        for (int j = 0; j < 4; ++j) acc[i][j] = (f32x4){0.f, 0.f, 0.f, 0.f};

    STAGE256(0, 0);
    const int NT = K >> 6;
    for (int T = 0; T < NT; ++T) {
        const int d = T & 1;
        if (T + 1 < NT) {
            STAGE256(d ^ 1, (T + 1) << 6);
            asm volatile("s_waitcnt vmcnt(8)" ::: "memory");
        } else {
            asm volatile("s_waitcnt vmcnt(0)" ::: "memory");
        }
        __builtin_amdgcn_s_barrier();
        __builtin_amdgcn_sched_barrier(0);
        __builtin_amdgcn_s_setprio(1);
        {
            const u16* Abase = &As[d][wm][0];
            const u16* Bbase = &Bs[d][wn >> 1][(wn & 1) * 4096];
            s16x8 bv[4][2];
#pragma unroll
            for (int fn = 0; fn < 4; ++fn) {
                bv[fn][0] = *(const s16x8*)(const void*)(Bbase + fn * 1024 + rbS0);
                bv[fn][1] = *(const s16x8*)(const void*)(Bbase + fn * 1024 + rbS1);
            }
#pragma unroll
            for (int h = 0; h < 2; ++h) {
                s16x8 av[4][2];
#pragma unroll
                for (int fm = 0; fm < 4; ++fm) {
                    av[fm][0] = *(const s16x8*)(const void*)(Abase + (h * 4 + fm) * 1024 + rbS0);
                    av[fm][1] = *(const s16x8*)(const void*)(Abase + (h * 4 + fm) * 1024 + rbS1);
                }
#pragma unroll
                for (int fm = 0; fm < 4; ++fm)
#pragma unroll
                    for (int fn = 0; fn < 4; ++fn) {
                        acc[h * 4 + fm][fn] = __builtin_amdgcn_mfma_f32_16x16x32_bf16(
                            av[fm][0], bv[fn][0], acc[h * 4 + fm][fn], 0, 0, 0);
                        acc[h * 4 + fm][fn] = __builtin_amdgcn_mfma_f32_16x16x32_bf16(
                            av[fm][1], bv[fn][1], acc[h * 4 + fm][fn], 0, 0, 0);
                    }
            }
        }
        __builtin_amdgcn_s_setprio(0);
        __builtin_amdgcn_sched_barrier(0);
        __builtin_amdgcn_s_barrier();
    }
#undef STAGE256

    // ---- epilogue ----
#pragma unroll
    for (int fm = 0; fm < 8; ++fm) {
#pragma unroll
        for (int r = 0; r < 4; ++r) {
            const int gm = m0 + wm * 128 + fm * 16 + g4 * 4 + r;
#pragma unroll
            for (int fn = 0; fn < 4; ++fn) {
                const int gn = n0 + wn * 64 + fn * 16 + fr;
                const float v = acc[fm][fn][r];
                const long off = (long)z * sOz + (long)gm * ldc + gn;
                if (EPI == E_BF16) {
                    outb[off] = f2bf(v);
                } else {  // E_SMIX
                    const float pre = bf2f(aux1b[off]);
                    outb[off]  = f2bf(pre + 0.5f * __logf(v + 1e-6f));  // Smix
                    outb2[off] = f2bf(v);                               // C2
                }
            }
        }
    }
}

// ============================================================================
// 128x128-tile 2-phase GEMM (all other matmuls) — unchanged from round 4.
// ============================================================================
template<int EPI>
__global__ __launch_bounds__(256) void gemm_nt(
    const u16* __restrict__ A, const u16* __restrict__ B,
    long sAz, long sBz, int lda, int ldb,
    int M, int Ncols, int K,
    float* __restrict__ outf, u16* __restrict__ outb,
    u16* __restrict__ outb2, u16* __restrict__ outb3,
    const float* __restrict__ aux1f, const u16* __restrict__ aux1b,
    const float* __restrict__ chainp,
    long sOz, int ldc, float scale, int zbase)
{
    __shared__ __align__(16) u16 As[2][BM * BK];
    __shared__ __align__(16) u16 Bs[2][BN * BK];

    const int z    = blockIdx.z;
    const u16* Ab  = A + (long)z * sAz;
    const u16* Bb  = B + (long)z * sBz;
    const int tid  = threadIdx.x;
    const int lane = tid & 63;
    const int wid  = tid >> 6;
    const int m0   = blockIdx.x * BM;
    const int n0   = blockIdx.y * BN;
    const int wr   = (wid >> 1) * 64;
    const int wc   = (wid & 1) * 64;

    f32x4 zero = {0.f, 0.f, 0.f, 0.f};
    f32x4 acc[4][4];
#pragma unroll
    for (int i = 0; i < 4; ++i)
#pragma unroll
        for (int j = 0; j < 4; ++j) acc[i][j] = zero;

    const int srow = tid >> 2;
    const int scol = (tid & 3) * 8;
    int bn0 = n0 + srow;      if (bn0 > Ncols - 1) bn0 = Ncols - 1;
    int bn1 = n0 + 64 + srow; if (bn1 > Ncols - 1) bn1 = Ncols - 1;
    const u16* gA0 = Ab + (long)(m0 + srow) * lda + scol;
    const u16* gA1 = Ab + (long)(m0 + 64 + srow) * lda + scol;
    const u16* gB0 = Bb + (long)bn0 * ldb + scol;
    const u16* gB1 = Bb + (long)bn1 * ldb + scol;

    const int kq = (lane >> 4) * 8;
    const int fr = lane & 15;

#define STAGE(buf, kk)                                  \
    do {                                                \
        g2lds16(gA0 + (kk), &As[buf][tid * 8]);         \
        g2lds16(gA1 + (kk), &As[buf][2048 + tid * 8]);  \
        g2lds16(gB0 + (kk), &Bs[buf][tid * 8]);         \
        g2lds16(gB1 + (kk), &Bs[buf][2048 + tid * 8]);  \
    } while (0)

    STAGE(0, 0);
    __syncthreads();
    int cur = 0;
    for (int k0 = 0; k0 < K; k0 += BK) {
        if (k0 + BK < K) STAGE(cur ^ 1, k0 + BK);
        s16x8 af[4], bfr[4];
#pragma unroll
        for (int i = 0; i < 4; ++i)
            af[i] = *(const s16x8*)(const void*)(&As[cur][(wr + i * 16 + fr) * BK + kq]);
#pragma unroll
        for (int j = 0; j < 4; ++j)
            bfr[j] = *(const s16x8*)(const void*)(&Bs[cur][(wc + j * 16 + fr) * BK + kq]);
#pragma unroll
        for (int i = 0; i < 4; ++i)
#pragma unroll
            for (int j = 0; j < 4; ++j)
                acc[i][j] = __builtin_amdgcn_mfma_f32_16x16x32_bf16(af[i], bfr[j], acc[i][j], 0, 0, 0);
        __syncthreads();
        cur ^= 1;
    }
#undef STAGE

    const int rbase = (lane >> 4) * 4;
    const int cidx  = lane & 15;
    float wgate = 0.f;
    if (EPI == E_Y) wgate = 1.f / (1.f + __expf(-chainp[0]));

#pragma unroll
    for (int i = 0; i < 4; ++i) {
#pragma unroll
        for (int r = 0; r < 4; ++r) {
            const int gm = m0 + wr + i * 16 + rbase + r;
#pragma unroll
            for (int j = 0; j < 4; ++j) {
                const int gn = n0 + wc + j * 16 + cidx;
                const float v = acc[i][j][r];
                if (EPI == E_F32) {
                    if (gn < Ncols) outf[(long)z * sOz + (long)gm * ldc + gn] = v * scale;
                } else if (EPI == E_BF16) {
                    if (gn < Ncols) outb[(long)z * sOz + (long)gm * ldc + gn] = f2bf(v * scale);
                } else if (EPI == E_QKV) {
                    const int b_ = gm >> 11, ntok = gm & 2047;
                    const int which = gn >> 9, h = (gn & 511) >> 6, d = gn & 63;
                    const long bh = (long)(b_ * 8 + h);
                    const u16 bv = f2bf(which == 0 ? v * scale : v);  // fold 1/sqrt(dk) into Q
                    if (which == 0)       outb [(bh * 2048 + ntok) * 64 + d] = bv;
                    else if (which == 1)  outb2[(bh * 2048 + ntok) * 64 + d] = bv;
                    else                  outb3[(bh * 64 + d) * 2048 + ntok] = bv;
                } else if (EPI == E_SMIX) {
                    const long off = (long)z * sOz + (long)gm * ldc + gn;
                    const float pre = bf2f(aux1b[off]);
                    outb[off]  = f2bf(pre + 0.5f * __logf(v + 1e-6f));
                    outb2[off] = f2bf(v);
                } else if (EPI == E_Y) {
                    if (gn < Ncols) {
                        const float yv = v + wgate * aux1f[(long)z * sOz + (long)gm * 64 + gn];
                        const int zg = zbase + z;
                        const int b_ = zg >> 3, h = zg & 7;
                        outb[((long)(b_ * 2048 + gm)) * 512 + h * 64 + gn] = f2bf(yv);
                    }
                }
            }
        }
    }
}

__global__ __launch_bounds__(256) void cvt_f32_bf16(const float* __restrict__ in,
                                                    u16* __restrict__ out, long n) {
    long i = (long)blockIdx.x * 256 + threadIdx.x;
    if (i < n) out[i] = f2bf(in[i]);
}

// in: [R][C] f32  ->  out: [C][R] bf16
__global__ __launch_bounds__(256) void cvt_transpose(const float* __restrict__ in,
                                                     u16* __restrict__ out, int R, int C) {
    long i = (long)blockIdx.x * 256 + threadIdx.x;
    if (i < (long)R * C) {
        int c = (int)(i / R), r = (int)(i % R);
        out[i] = f2bf(in[(long)r * C + c]);
    }
}

// per-z transpose of 2048x2048 bf16
__global__ __launch_bounds__(256) void trans2048(const u16* __restrict__ in,
                                                 u16* __restrict__ out) {
    __shared__ u16 tile[64][65];
    const long z = blockIdx.z;
    const u16* I = in + z * (long)2048 * 2048;
    u16* O       = out + z * (long)2048 * 2048;
    const int bx = blockIdx.x * 64, by = blockIdx.y * 64;
    const int t = threadIdx.x, c = t & 63, r4 = t >> 6;
#pragma unroll
    for (int s = 0; s < 16; ++s) {
        int r = s * 4 + r4;
        tile[r][c] = I[(long)(by + r) * 2048 + bx + c];
    }
    __syncthreads();
#pragma unroll
    for (int s = 0; s < 16; ++s) {
        int r = s * 4 + r4;
        O[(long)(bx + r) * 2048 + by + c] = tile[c][r];
    }
}

// One block per row (2048 bf16). MODE 0: A = softmax(S).
// MODE 1: A = softmax(S);  PreOut = 0.5*Spre + 0.75*S + 0.5*logaddexp(Spre,S)
template<int MODE>
__global__ __launch_bounds__(256) void row_softmax_bf(
    const u16* __restrict__ S, const u16* __restrict__ Spre,
    u16* __restrict__ A, u16* __restrict__ PreOut)
{
    const long row = blockIdx.x;
    const u16* p = S + row * 2048;
    const int t = threadIdx.x;
    s16x8 xv = *(const s16x8*)(const void*)(p + t * 8);
    float x[8];
#pragma unroll
    for (int e = 0; e < 8; ++e) x[e] = bf2f((u16)xv[e]);
    float m = x[0];
#pragma unroll
    for (int e = 1; e < 8; ++e) m = fmaxf(m, x[e]);
#pragma unroll
    for (int off = 32; off >= 1; off >>= 1) m = fmaxf(m, __shfl_xor(m, off));
    __shared__ float red[8];
    if ((t & 63) == 0) red[t >> 6] = m;
    __syncthreads();
    m = fmaxf(fmaxf(red[0], red[1]), fmaxf(red[2], red[3]));
    float s = 0.f, ee[8];
#pragma unroll
    for (int e = 0; e < 8; ++e) { ee[e] = __expf(x[e] - m); s += ee[e]; }
#pragma unroll
    for (int off = 32; off >= 1; off >>= 1) s += __shfl_xor(s, off);
    if ((t & 63) == 0) red[4 + (t >> 6)] = s;
    __syncthreads();
    s = red[4] + red[5] + red[6] + red[7];
    const float inv = 1.f / s;
    s16x8 o;
#pragma unroll
    for (int e = 0; e < 8; ++e) o[e] = (short)f2bf(ee[e] * inv);
    *(s16x8*)(void*)(A + row * 2048 + t * 8) = o;

    if (MODE == 1) {
        s16x8 pv = *(const s16x8*)(const void*)(Spre + row * 2048 + t * 8);
        s16x8 po;
#pragma unroll
        for (int e = 0; e < 8; ++e) {
            const float s1 = bf2f((u16)pv[e]);
            const float s2 = x[e];
            const float mx = fmaxf(s1, s2);
            const float lae = mx + log1pf(__expf(-fabsf(s1 - s2)));
            po[e] = (short)f2bf(0.5f * s1 + 0.75f * s2 + 0.5f * lae);
        }
        *(s16x8*)(void*)(PreOut + row * 2048 + t * 8) = po;
    }
}

extern "C" void kernel_launch(void* const* d_in, const int* in_sizes, int n_in,
                              void* d_out, int out_size, void* d_ws, size_t ws_size,
                              hipStream_t stream) {
    const float* x  = (const float*)d_in[0];
    const float* W1 = (const float*)d_in[1];
    const float* W2 = (const float*)d_in[2];
    const float* Wp = (const float*)d_in[3];
    const float* ch = (const float*)d_in[4];

    const int Bq = 2, N = 2048, D = 512, dk = 64, Z = 16;
    const long NN = (long)N * N;
    const long ND = (long)N * dk;
    (void)in_sizes; (void)n_in; (void)out_size;

    size_t ws_avail = ws_size ? ws_size : (size_t)-1;

    char* w = (char*)d_ws;
    size_t off = 0;
    auto alc = [&](size_t bytes) -> void* {
        void* p = w + off;
        off += (bytes + 255) & ~(size_t)255;
        return p;
    };

    // ---- persistent (~36 MiB) ----
    u16* xb   = (u16*)alc((long)Bq * N * D * 2);
    u16* W1t  = (u16*)alc((long)3 * D * D * 2);
    u16* W2t  = (u16*)alc((long)3 * D * D * 2);
    u16* Wpt  = (u16*)alc((long)D * D * 2);
    u16* Q1   = (u16*)alc(Z * ND * 2);
    u16* K1   = (u16*)alc(Z * ND * 2);
    u16* V1t  = (u16*)alc(Z * ND * 2);
    u16* Q2   = (u16*)alc(Z * ND * 2);
    u16* K2   = (u16*)alc(Z * ND * 2);
    u16* V2t  = (u16*)alc(Z * ND * 2);
    u16* y    = (u16*)alc((long)Bq * N * D * 2);
    const size_t persist = off;

    const size_t perz = 4 * (size_t)(NN * 2) + (size_t)(ND * 4) + 4096;
    int G = 16;
    while (G > 1 && persist + (size_t)G * perz + 65536 > ws_avail) G >>= 1;

    u16*  S1b = (u16*)alc((size_t)G * NN * 2);   // S1 -> Pre -> Smix
    u16*  S2b = (u16*)alc((size_t)G * NN * 2);   // S2 -> A2t
    u16*  A1b = (u16*)alc((size_t)G * NN * 2);   // A1 -> C2
    u16*  C1b = (u16*)alc((size_t)G * NN * 2);   // A2 -> C1 -> final A
    float* yc = (float*)alc((size_t)G * ND * 4);

    const dim3 blk(256);
    const float iscale = 0.125f;  // 1/sqrt(64)

    cvt_f32_bf16<<<(unsigned)(((long)Bq * N * D + 255) / 256), blk, 0, stream>>>(x, xb, (long)Bq * N * D);
    cvt_transpose<<<(3 * D * D + 255) / 256, blk, 0, stream>>>(W1, W1t, D, 3 * D);
    cvt_transpose<<<(3 * D * D + 255) / 256, blk, 0, stream>>>(W2, W2t, D, 3 * D);
    cvt_transpose<<<(D * D + 255) / 256, blk, 0, stream>>>(Wp, Wpt, D, D);

    gemm_nt<E_QKV><<<dim3(32, 12, 1), blk, 0, stream>>>(
        xb, W1t, 0L, 0L, D, D, Bq * N, 3 * D, D,
        nullptr, Q1, K1, V1t, nullptr, nullptr, nullptr, 0L, 0, iscale, 0);
    gemm_nt<E_QKV><<<dim3(32, 12, 1), blk, 0, stream>>>(
        xb, W2t, 0L, 0L, D, D, Bq * N, 3 * D, D,
        nullptr, Q2, K2, V2t, nullptr, nullptr, nullptr, 0L, 0, iscale, 0);

    for (int zb = 0; zb < Z; zb += G) {
        const u16* Q1z = Q1 + (long)zb * ND;
        const u16* K1z = K1 + (long)zb * ND;
        const u16* V1z = V1t + (long)zb * ND;
        const u16* Q2z = Q2 + (long)zb * ND;
        const u16* K2z = K2 + (long)zb * ND;
        const u16* V2z = V2t + (long)zb * ND;

        // S1 = Q1 K1^T (scale folded into Q) -> S1b ; S2 -> S2b  (bf16)
        gemm_nt<E_BF16><<<dim3(16, 16, G), blk, 0, stream>>>(
            Q1z, K1z, ND, ND, dk, dk, N, N, dk,
            nullptr, S1b, nullptr, nullptr, nullptr, nullptr, nullptr, NN, N, 1.f, 0);
        gemm_nt<E_BF16><<<dim3(16, 16, G), blk, 0, stream>>>(
            Q2z, K2z, ND, ND, dk, dk, N, N, dk,
            nullptr, S2b, nullptr, nullptr, nullptr, nullptr, nullptr, NN, N, 1.f, 0);

        // A1 = softmax(S1) -> A1b ; A2 = softmax(S2) -> C1b, Pre -> S1b (in-place)
        row_softmax_bf<0><<<G * N, blk, 0, stream>>>(S1b, nullptr, A1b, nullptr);
        row_softmax_bf<1><<<G * N, blk, 0, stream>>>(S2b, S1b, C1b, S1b);

        // A2t: C1b(A2) -> S2b
        trans2048<<<dim3(32, 32, G), blk, 0, stream>>>(C1b, S2b);

        // C1 = A1 @ A2  -> C1b   (256^2 pipelined kernel)
        gemm256_nt<E_BF16><<<dim3(8, 8, G), dim3(512), 0, stream>>>(
            A1b, S2b, NN, NN, N, N, N,
            C1b, nullptr, nullptr, NN, N);
        // C2 = C1 @ A2 ; Smix = Pre + 0.5*log(C2+eps) -> S1b ; C2 bf16 -> A1b
        gemm256_nt<E_SMIX><<<dim3(8, 8, G), dim3(512), 0, stream>>>(
            C1b, S2b, NN, NN, N, N, N,
            S1b, A1b, S1b, NN, N);
        // A = softmax(Smix) -> C1b
        row_softmax_bf<0><<<G * N, blk, 0, stream>>>(S1b, nullptr, C1b, nullptr);

        // y_chain = C2 @ v2  (f32 [z][N][64])
        gemm_nt<E_F32><<<dim3(16, 1, G), blk, 0, stream>>>(
            A1b, V2z, NN, ND, N, N, N, dk, N,
            yc, nullptr, nullptr, nullptr, nullptr, nullptr, nullptr, ND, dk, 1.f, 0);
        // y = A @ v1 + sigmoid(chain)*y_chain  -> bf16 [B,N,D]
        gemm_nt<E_Y><<<dim3(16, 1, G), blk, 0, stream>>>(
            C1b, V1z, NN, ND, N, N, N, dk, N,
            nullptr, y, nullptr, nullptr, yc, nullptr, ch, ND, dk, 1.f, zb);
    }

    // out = y @ Wproj   (f32)
    gemm_nt<E_F32><<<dim3(32, 4, 1), blk, 0, stream>>>(
        y, Wpt, 0L, 0L, D, D, Bq * N, D, D,
        (float*)d_out, nullptr, nullptr, nullptr, nullptr, nullptr, nullptr, 0L, D, 1.f, 0);
}